// Round 9
// baseline (1341.434 us; speedup 1.0000x reference)
//
#include <hip/hip_runtime.h>

#define HD 256   // hidden dim H

typedef __attribute__((ext_vector_type(8))) __bf16 bf16x8;
typedef __attribute__((ext_vector_type(4))) __bf16 bf16x4;
typedef __attribute__((ext_vector_type(4))) float f32x4;

static __device__ __forceinline__ float relu_f(float x){ return x > 0.f ? x : 0.f; }

// split fp32x4 -> bf16 hi/lo
static __device__ __forceinline__ void split4(const float* m, bf16x4& vh, bf16x4& vl){
    #pragma unroll
    for (int j = 0; j < 4; j++){
        float v = m[j];
        __bf16 h = (__bf16)v;
        vh[j] = h;
        vl[j] = (__bf16)(v - (float)h);
    }
}

// ---------------- CSR build ----------------
__global__ void k_count(const int* __restrict__ dst, int* __restrict__ cnt, int E){
    int i = blockIdx.x * blockDim.x + threadIdx.x;
    if (i < E) atomicAdd(&cnt[dst[i]], 1);
}

// single-block chunked Hillis-Steele exclusive scan; also emits dinv = 1/sqrt(deg+1)
__global__ void k_scan(const int* __restrict__ cnt, int* __restrict__ row_ptr,
                       float* __restrict__ dinv, int n){
    __shared__ int lds[1024];
    int t = threadIdx.x;
    int carry = 0;
    for (int base = 0; base < n; base += 1024){
        int idx = base + t;
        int v = (idx < n) ? cnt[idx] : 0;
        if (idx < n) dinv[idx] = 1.0f / sqrtf((float)(v + 1));
        __syncthreads();
        lds[t] = v;
        __syncthreads();
        for (int off = 1; off < 1024; off <<= 1){
            int add = (t >= off) ? lds[t - off] : 0;
            __syncthreads();
            lds[t] += add;
            __syncthreads();
        }
        int incl = lds[t];
        if (idx < n) row_ptr[idx] = carry + incl - v;   // exclusive
        carry += lds[1023];
    }
    if (t == 0) row_ptr[n] = carry;
}

__global__ void k_fill(const int* __restrict__ src, const int* __restrict__ dst,
                       const int* __restrict__ row_ptr, int* __restrict__ fill,
                       int* __restrict__ csr_src, int* __restrict__ csr_dst, int E){
    int i = blockIdx.x * blockDim.x + threadIdx.x;
    if (i < E){
        int d = dst[i];
        int pos = row_ptr[d] + atomicAdd(&fill[d], 1);
        csr_src[pos] = src[i];
        csr_dst[pos] = d;
    }
}

// ---------------- fused weight pack: fragment-ordered bf16 hi/lo, all weights in one launch ----
// Wp[((ks*256 + c)*4 + g)*8 + j] = W[ks*32 + g*8 + j][c]; optional src2 -> pack (src - src2).
struct PackDesc { const float* src; const float* src2; __bf16* ph; __bf16* pl; int K; int pad; };
struct PackArgs { PackDesc d[10]; };

__global__ void k_wpack_all(PackArgs a){
    PackDesc p = a.d[blockIdx.y];
    int total = (p.K >> 5) * 8192;
    int idx = blockIdx.x * 256 + threadIdx.x;
    if (idx >= total) return;
    int j = idx & 7, g = (idx >> 3) & 3, c = (idx >> 5) & 255, ks = idx >> 13;
    int k = ks * 32 + g * 8 + j;
    float v = p.src[(size_t)k * HD + c];
    if (p.src2) v -= p.src2[(size_t)k * HD + c];
    __bf16 h = (__bf16)v;
    p.ph[idx] = h;
    p.pl[idx] = (__bf16)(v - (float)h);
}

// ---------------- MFMA node GEMM: C[M,256] = A[M,K] @ W (+bias) ----------------
// 512 threads / 8 waves; wave w -> cols [32w, 32w+32); full row segment preloaded to regs
// (KS*4 VGPRs) so no load latency inside the k-loop.
template<int KS>
__global__ __launch_bounds__(512, 4) void k_gemm_mfma(
    const float* __restrict__ A,
    const __bf16* __restrict__ Wph, const __bf16* __restrict__ Wpl,
    const float* __restrict__ bias,
    float* __restrict__ C, int M, int K)
{
    __shared__ __bf16 mh[2][64][40];   // row stride 80B
    __shared__ __bf16 ml[2][64][40];
    int t = threadIdx.x;
    int m0 = blockIdx.x * 64;
    const int w = t >> 6, fr = t & 15, fg = (t & 63) >> 4;
    const int srow = t >> 3, skb = (t & 7) * 4;      // 8 threads cover 32 k per row
    int ar = m0 + srow; if (ar >= M) ar = M - 1;     // clamp loads; stores guarded
    const float* Arow = A + (size_t)ar * K + skb;
    const int c0 = w * 32 + fr;

    auto stage = [&](int buf, const float4& a){
        float m4[4] = {a.x, a.y, a.z, a.w};
        bf16x4 vh, vl;
        split4(m4, vh, vl);
        *(bf16x4*)&mh[buf][srow][skb] = vh;
        *(bf16x4*)&ml[buf][srow][skb] = vl;
    };

    f32x4 acc[4][2];
    #pragma unroll
    for (int i = 0; i < 4; i++)
        #pragma unroll
        for (int j = 0; j < 2; j++) acc[i][j] = (f32x4){0.f, 0.f, 0.f, 0.f};

    float4 rA[KS];
    #pragma unroll
    for (int c = 0; c < KS; c++) rA[c] = *(const float4*)(Arow + c * 32);

    stage(0, rA[0]);

    #pragma unroll
    for (int ks = 0; ks < KS; ++ks){
        bf16x8 bh[2], bl[2];
        #pragma unroll
        for (int nf = 0; nf < 2; nf++){
            size_t bi = ((size_t)(ks * 256 + c0 + nf * 16) * 4 + fg) * 8;
            bh[nf] = *(const bf16x8*)(Wph + bi);
            bl[nf] = *(const bf16x8*)(Wpl + bi);
        }
        __syncthreads();             // buf[ks&1] staged; prev readers of buf[(ks+1)&1] done
        const int cb = ks & 1;
        #pragma unroll
        for (int mf = 0; mf < 4; mf++){
            bf16x8 ah = *(const bf16x8*)&mh[cb][mf * 16 + fr][fg * 8];
            bf16x8 al = *(const bf16x8*)&ml[cb][mf * 16 + fr][fg * 8];
            #pragma unroll
            for (int nf = 0; nf < 2; nf++){
                acc[mf][nf] = __builtin_amdgcn_mfma_f32_16x16x32_bf16(ah, bh[nf], acc[mf][nf], 0, 0, 0);
                acc[mf][nf] = __builtin_amdgcn_mfma_f32_16x16x32_bf16(al, bh[nf], acc[mf][nf], 0, 0, 0);
                acc[mf][nf] = __builtin_amdgcn_mfma_f32_16x16x32_bf16(ah, bl[nf], acc[mf][nf], 0, 0, 0);
            }
        }
        if (ks + 1 < KS) stage(cb ^ 1, rA[ks + 1]);
    }

    float bj[2];
    #pragma unroll
    for (int nf = 0; nf < 2; nf++) bj[nf] = bias ? bias[c0 + nf * 16] : 0.f;
    #pragma unroll
    for (int mf = 0; mf < 4; mf++)
        #pragma unroll
        for (int reg = 0; reg < 4; reg++){
            int row = m0 + mf * 16 + fg * 4 + reg;   // C/D: col=lane&15, row=fg*4+reg (verified)
            if (row < M){
                #pragma unroll
                for (int nf = 0; nf < 2; nf++)
                    C[(size_t)row * HD + c0 + nf * 16] = acc[mf][nf][reg] + bj[nf];
            }
        }
}

// ---------------- GCN aggregate: 4 independent load/acc chains per wave ----------------
__global__ __launch_bounds__(256) void k_gcn_agg(const float* __restrict__ h,
                                                 const float* __restrict__ dinv,
                                                 const int* __restrict__ row_ptr,
                                                 const int* __restrict__ csr_src,
                                                 const float* __restrict__ bias,
                                                 float* __restrict__ out, int n){
    int wid = threadIdx.x >> 6, lane = threadIdx.x & 63;
    int i = blockIdx.x * 4 + wid;
    if (i >= n) return;
    float di = dinv[i];
    const float4* hp = (const float4*)h;
    float4 v = hp[(size_t)i * 64 + lane];
    float ax0 = v.x * di, ay0 = v.y * di, az0 = v.z * di, aw0 = v.w * di;  // self loop
    float ax1 = 0.f, ay1 = 0.f, az1 = 0.f, aw1 = 0.f;
    float ax2 = 0.f, ay2 = 0.f, az2 = 0.f, aw2 = 0.f;
    float ax3 = 0.f, ay3 = 0.f, az3 = 0.f, aw3 = 0.f;
    int e0 = row_ptr[i], e1 = row_ptr[i + 1];
    int e = e0;
    for (; e + 3 < e1; e += 4){
        int s0 = csr_src[e], s1 = csr_src[e + 1], s2 = csr_src[e + 2], s3 = csr_src[e + 3];
        float q0 = dinv[s0], q1 = dinv[s1], q2 = dinv[s2], q3 = dinv[s3];
        float4 u0 = hp[(size_t)s0 * 64 + lane];
        float4 u1 = hp[(size_t)s1 * 64 + lane];
        float4 u2 = hp[(size_t)s2 * 64 + lane];
        float4 u3 = hp[(size_t)s3 * 64 + lane];
        ax0 += u0.x * q0; ay0 += u0.y * q0; az0 += u0.z * q0; aw0 += u0.w * q0;
        ax1 += u1.x * q1; ay1 += u1.y * q1; az1 += u1.z * q1; aw1 += u1.w * q1;
        ax2 += u2.x * q2; ay2 += u2.y * q2; az2 += u2.z * q2; aw2 += u2.w * q2;
        ax3 += u3.x * q3; ay3 += u3.y * q3; az3 += u3.z * q3; aw3 += u3.w * q3;
    }
    for (; e < e1; e++){
        int s = csr_src[e];
        float q = dinv[s];
        float4 u = hp[(size_t)s * 64 + lane];
        ax0 += u.x * q; ay0 += u.y * q; az0 += u.z * q; aw0 += u.w * q;
    }
    float ax = (ax0 + ax1) + (ax2 + ax3);
    float ay = (ay0 + ay1) + (ay2 + ay3);
    float az = (az0 + az1) + (az2 + az3);
    float aw = (aw0 + aw1) + (aw2 + aw3);
    const float4 b = ((const float4*)bias)[lane];
    float4 o;
    o.x = relu_f(ax * di + b.x);
    o.y = relu_f(ay * di + b.y);
    o.z = relu_f(az * di + b.z);
    o.w = relu_f(aw * di + b.w);
    ((float4*)out)[(size_t)i * 64 + lane] = o;
}

// ---------------- fused EdgeConv: MFMA edge GEMM + max-aggregate (v4) ----------------
// 512 threads / 8 waves / 32 cols per wave; XCD-bijective swizzle; 4-deep register ring
// prefetch for the A/B gathers (each chunk's load issued ~4 barrier-phases before use).
__global__ __launch_bounds__(512, 4) void k_edge_mfma(
    const float* __restrict__ A, const float* __restrict__ B,
    const __bf16* __restrict__ Wph, const __bf16* __restrict__ Wpl,
    const float* __restrict__ bias,
    const int* __restrict__ csr_src, const int* __restrict__ csr_dst,
    float* __restrict__ out, int E)
{
    __shared__ __bf16 mh[2][64][40];
    __shared__ __bf16 ml[2][64][40];
    __shared__ int sdst[64], ssrc[64];
    int t = threadIdx.x;
    // XCD-contiguous bijective swizzle (m204)
    int nwg = gridDim.x;
    int q = nwg >> 3, r = nwg & 7;
    int xc = blockIdx.x & 7;
    int bid = (xc < r ? xc * (q + 1) : r * (q + 1) + (xc - r) * q) + (blockIdx.x >> 3);
    int p0 = bid * 64;
    if (t < 64){
        int e = p0 + t; if (e >= E) e = E - 1;   // duplicate edge: idempotent under max
        sdst[t] = csr_dst[e];
        ssrc[t] = csr_src[e];
    }
    __syncthreads();

    const int w  = t >> 6;
    const int fr = t & 15;
    const int fg = (t & 63) >> 4;
    const int srow = t >> 3, skb = (t & 7) * 4;
    const float* Arow = A + (size_t)sdst[srow] * HD + skb;
    const float* Brow = B + (size_t)ssrc[srow] * HD + skb;
    const int c0 = w * 32 + fr;

    auto stage = [&](int buf, const float4& a, const float4& g){
        float m4[4] = {relu_f(a.x + g.x), relu_f(a.y + g.y), relu_f(a.z + g.z), relu_f(a.w + g.w)};
        bf16x4 vh, vl;
        split4(m4, vh, vl);
        *(bf16x4*)&mh[buf][srow][skb] = vh;
        *(bf16x4*)&ml[buf][srow][skb] = vl;
    };

    f32x4 acc[4][2];
    #pragma unroll
    for (int i = 0; i < 4; i++)
        #pragma unroll
        for (int j = 0; j < 2; j++) acc[i][j] = (f32x4){0.f, 0.f, 0.f, 0.f};

    // 4-deep gather ring (ra/rg[c] holds chunk whose index ≡ c mod 4)
    float4 ra[4], rg[4];
    #pragma unroll
    for (int c = 0; c < 4; c++){
        ra[c] = *(const float4*)(Arow + c * 32);
        rg[c] = *(const float4*)(Brow + c * 32);
    }
    stage(0, ra[0], rg[0]);

    #pragma unroll
    for (int ks = 0; ks < 8; ++ks){
        if (ks + 4 < 8){                       // refill ring slot (chunk ks already staged)
            ra[ks & 3] = *(const float4*)(Arow + (ks + 4) * 32);
            rg[ks & 3] = *(const float4*)(Brow + (ks + 4) * 32);
        }
        bf16x8 bh[2], bl[2];
        #pragma unroll
        for (int nf = 0; nf < 2; nf++){
            size_t bi = ((size_t)(ks * 256 + c0 + nf * 16) * 4 + fg) * 8;
            bh[nf] = *(const bf16x8*)(Wph + bi);
            bl[nf] = *(const bf16x8*)(Wpl + bi);
        }
        __syncthreads();             // buf[ks&1] staged; prev readers of buf[(ks+1)&1] done
        const int cb = ks & 1;
        #pragma unroll
        for (int mf = 0; mf < 4; mf++){
            bf16x8 ah = *(const bf16x8*)&mh[cb][mf * 16 + fr][fg * 8];
            bf16x8 al = *(const bf16x8*)&ml[cb][mf * 16 + fr][fg * 8];
            #pragma unroll
            for (int nf = 0; nf < 2; nf++){
                acc[mf][nf] = __builtin_amdgcn_mfma_f32_16x16x32_bf16(ah, bh[nf], acc[mf][nf], 0, 0, 0);
                acc[mf][nf] = __builtin_amdgcn_mfma_f32_16x16x32_bf16(al, bh[nf], acc[mf][nf], 0, 0, 0);
                acc[mf][nf] = __builtin_amdgcn_mfma_f32_16x16x32_bf16(ah, bl[nf], acc[mf][nf], 0, 0, 0);
            }
        }
        if (ks < 7) stage(cb ^ 1, ra[(ks + 1) & 3], rg[(ks + 1) & 3]);
    }

    // epilogue: run-tracking scan over this thread's 16 rows (sdst non-decreasing in CSR order)
    float bj[2];
    #pragma unroll
    for (int nf = 0; nf < 2; nf++) bj[nf] = bias[c0 + nf * 16];
    int curd = sdst[fg * 4];
    float v[2];
    #pragma unroll
    for (int nf = 0; nf < 2; nf++) v[nf] = acc[0][nf][0] + bj[nf];
    #pragma unroll
    for (int mf = 0; mf < 4; mf++){
        #pragma unroll
        for (int reg = 0; reg < 4; reg++){
            if (mf == 0 && reg == 0) continue;
            int d = sdst[mf * 16 + fg * 4 + reg];
            if (d != curd){
                #pragma unroll
                for (int nf = 0; nf < 2; nf++)
                    if (v[nf] > 0.f)
                        atomicMax((int*)(out + (size_t)curd * HD + c0 + nf * 16), __float_as_int(v[nf]));
                curd = d;
                #pragma unroll
                for (int nf = 0; nf < 2; nf++) v[nf] = acc[mf][nf][reg] + bj[nf];
            } else {
                #pragma unroll
                for (int nf = 0; nf < 2; nf++) v[nf] = fmaxf(v[nf], acc[mf][nf][reg] + bj[nf]);
            }
        }
    }
    #pragma unroll
    for (int nf = 0; nf < 2; nf++)
        if (v[nf] > 0.f)
            atomicMax((int*)(out + (size_t)curd * HD + c0 + nf * 16), __float_as_int(v[nf]));
}

// ---------------- fused per-graph sum pool + head ----------------
__global__ __launch_bounds__(512) void k_pool_head(const float* __restrict__ xg,
                                                   const float* __restrict__ xe,
                                                   const int* __restrict__ batch,
                                                   const float* __restrict__ w1,
                                                   const float* __restrict__ b1,
                                                   const float* __restrict__ w2,
                                                   const float* __restrict__ b2,
                                                   float* __restrict__ out, int n){
    __shared__ float gp[512];
    __shared__ float red[256];
    int g = blockIdx.x, t = threadIdx.x;
    int lo, hi;
    { int l = 0, h = n; while (l < h){ int m = (l + h) >> 1; if (batch[m] < g) l = m + 1; else h = m; } lo = l; }
    { int l = lo, h = n; while (l < h){ int m = (l + h) >> 1; if (batch[m] < g + 1) l = m + 1; else h = m; } hi = l; }
    const float* sp = (t < 256) ? (xg + t) : (xe + (t - 256));
    float a0 = 0.f, a1 = 0.f;
    int i = lo;
    for (; i + 1 < hi; i += 2){
        a0 += sp[(size_t)i * HD];
        a1 += sp[(size_t)(i + 1) * HD];
    }
    if (i < hi) a0 += sp[(size_t)i * HD];
    gp[t] = a0 + a1;
    __syncthreads();
    if (t < 256){
        float acc = b1[t];
        #pragma unroll 4
        for (int k = 0; k < 512; k++) acc += gp[k] * w1[k * HD + t];
        red[t] = relu_f(acc) * w2[t];
    }
    __syncthreads();
    for (int s = 128; s > 0; s >>= 1){
        if (t < s) red[t] += red[t + s];
        __syncthreads();
    }
    if (t == 0) out[g] = red[0] + b2[0];
}

extern "C" void kernel_launch(void* const* d_in, const int* in_sizes, int n_in,
                              void* d_out, int out_size, void* d_ws, size_t ws_size,
                              hipStream_t stream){
    const float* x      = (const float*)d_in[0];
    const int*   ei     = (const int*)d_in[1];
    const int*   batch  = (const int*)d_in[2];
    const float* gcn_w[4] = {(const float*)d_in[3], (const float*)d_in[5], (const float*)d_in[7], (const float*)d_in[9]};
    const float* gcn_b[4] = {(const float*)d_in[4], (const float*)d_in[6], (const float*)d_in[8], (const float*)d_in[10]};
    const float* ec1_w1 = (const float*)d_in[11]; const float* ec1_b1 = (const float*)d_in[12];
    const float* ec1_w2 = (const float*)d_in[13]; const float* ec1_b2 = (const float*)d_in[14];
    const float* ec2_w1 = (const float*)d_in[15]; const float* ec2_b1 = (const float*)d_in[16];
    const float* ec2_w2 = (const float*)d_in[17]; const float* ec2_b2 = (const float*)d_in[18];
    const float* fc1_w  = (const float*)d_in[19]; const float* fc1_b  = (const float*)d_in[20];
    const float* out_w  = (const float*)d_in[21]; const float* out_b  = (const float*)d_in[22];

    const int N = in_sizes[2];
    const int E = in_sizes[1] / 2;
    const int F = in_sizes[0] / N;       // 128
    const int* src = ei;
    const int* dst = ei + E;
    const int GB64 = (N + 63) / 64;      // node-GEMM grid
    const int EB   = (E + 63) / 64;      // edge grid

    char* w = (char*)d_ws;
    auto alloc = [&](size_t bytes) -> char* {
        char* p = w;
        w += (bytes + 255) & ~(size_t)255;
        return p;
    };
    int*   cnt     = (int*)alloc((size_t)N * 4);
    int*   fillc   = (int*)alloc((size_t)N * 4);
    int*   row_ptr = (int*)alloc((size_t)(N + 1) * 4);
    int*   csr_src = (int*)alloc((size_t)E * 4);
    int*   csr_dst = (int*)alloc((size_t)E * 4);
    float* dinv    = (float*)alloc((size_t)N * 4);
    float* act     = (float*)alloc((size_t)N * HD * 4);
    float* hbuf    = (float*)alloc((size_t)N * HD * 4);
    float* Bbuf    = (float*)alloc((size_t)N * HD * 4);
    float* xebuf   = (float*)alloc((size_t)N * HD * 4);
    // weight packs (bf16 hi/lo, fragment-ordered)
    auto packa = [&](int K) -> __bf16* { return (__bf16*)alloc((size_t)K * 256 * 2); };
    __bf16* pg1h = packa(128); __bf16* pg1l = packa(128);
    __bf16* pg2h = packa(256); __bf16* pg2l = packa(256);
    __bf16* pg3h = packa(256); __bf16* pg3l = packa(256);
    __bf16* pg4h = packa(256); __bf16* pg4l = packa(256);
    __bf16* pe1ah = packa(128); __bf16* pe1al = packa(128);
    __bf16* pe1bh = packa(128); __bf16* pe1bl = packa(128);
    __bf16* pe2ah = packa(256); __bf16* pe2al = packa(256);
    __bf16* pe2bh = packa(256); __bf16* pe2bl = packa(256);
    __bf16* w2h1 = packa(256); __bf16* w2l1 = packa(256);
    __bf16* w2h2 = packa(256); __bf16* w2l2 = packa(256);

    // ---- CSR + deg norm ----
    hipMemsetAsync(cnt, 0, (size_t)N * 4, stream);
    hipMemsetAsync(fillc, 0, (size_t)N * 4, stream);
    k_count<<<(E + 255) / 256, 256, 0, stream>>>(dst, cnt, E);
    k_scan<<<1, 1024, 0, stream>>>(cnt, row_ptr, dinv, N);
    k_fill<<<(E + 255) / 256, 256, 0, stream>>>(src, dst, row_ptr, fillc, csr_src, csr_dst, E);

    // ---- all weight packs in ONE launch (wdiff folded in via src2) ----
    PackArgs pa;
    pa.d[0] = {gcn_w[0],                  nullptr,                    pg1h,  pg1l,  F,  0};
    pa.d[1] = {gcn_w[1],                  nullptr,                    pg2h,  pg2l,  HD, 0};
    pa.d[2] = {gcn_w[2],                  nullptr,                    pg3h,  pg3l,  HD, 0};
    pa.d[3] = {gcn_w[3],                  nullptr,                    pg4h,  pg4l,  HD, 0};
    pa.d[4] = {ec1_w1,                    ec1_w1 + (size_t)F * HD,    pe1ah, pe1al, F,  0};
    pa.d[5] = {ec1_w1 + (size_t)F * HD,   nullptr,                    pe1bh, pe1bl, F,  0};
    pa.d[6] = {ec2_w1,                    ec2_w1 + (size_t)HD * HD,   pe2ah, pe2al, HD, 0};
    pa.d[7] = {ec2_w1 + (size_t)HD * HD,  nullptr,                    pe2bh, pe2bl, HD, 0};
    pa.d[8] = {ec1_w2,                    nullptr,                    w2h1,  w2l1,  HD, 0};
    pa.d[9] = {ec2_w2,                    nullptr,                    w2h2,  w2l2,  HD, 0};
    k_wpack_all<<<dim3(256, 10), 256, 0, stream>>>(pa);

    // ---- GCN branch ----
    k_gemm_mfma<4><<<GB64, 512, 0, stream>>>(x, pg1h, pg1l, nullptr, hbuf, N, F);
    k_gcn_agg<<<(N + 3) / 4, 256, 0, stream>>>(hbuf, dinv, row_ptr, csr_src, gcn_b[0], act, N);
    const __bf16* pgh[3] = {pg2h, pg3h, pg4h};
    const __bf16* pgl[3] = {pg2l, pg3l, pg4l};
    for (int l = 0; l < 3; l++){
        k_gemm_mfma<8><<<GB64, 512, 0, stream>>>(act, pgh[l], pgl[l], nullptr, hbuf, N, HD);
        k_gcn_agg<<<(N + 3) / 4, 256, 0, stream>>>(hbuf, dinv, row_ptr, csr_src, gcn_b[l + 1], act, N);
    }

    // ---- EdgeConv 1 (input x, K=F) ----
    k_gemm_mfma<4><<<GB64, 512, 0, stream>>>(x, pe1ah, pe1al, ec1_b1, hbuf, N, F);   // A = x@(Wt-Wb)+b1
    k_gemm_mfma<4><<<GB64, 512, 0, stream>>>(x, pe1bh, pe1bl, nullptr, Bbuf, N, F);  // B = x@Wb
    hipMemsetAsync(xebuf, 0, (size_t)N * HD * 4, stream);
    k_edge_mfma<<<EB, 512, 0, stream>>>(hbuf, Bbuf, w2h1, w2l1, ec1_b2, csr_src, csr_dst, xebuf, E);

    // ---- EdgeConv 2 (input xe, K=HD) ----
    k_gemm_mfma<8><<<GB64, 512, 0, stream>>>(xebuf, pe2ah, pe2al, ec2_b1, hbuf, N, HD);
    k_gemm_mfma<8><<<GB64, 512, 0, stream>>>(xebuf, pe2bh, pe2bl, nullptr, Bbuf, N, HD);
    hipMemsetAsync(xebuf, 0, (size_t)N * HD * 4, stream);
    k_edge_mfma<<<EB, 512, 0, stream>>>(hbuf, Bbuf, w2h2, w2l2, ec2_b2, csr_src, csr_dst, xebuf, E);

    // ---- fused pool + head ----
    k_pool_head<<<64, 512, 0, stream>>>(act, xebuf, batch, fc1_w, fc1_b, out_w, out_b, (float*)d_out, N);
}

// Round 10
// 1279.072 us; speedup vs baseline: 1.0488x; 1.0488x over previous
//
#include <hip/hip_runtime.h>

#define HD 256   // hidden dim H

typedef __attribute__((ext_vector_type(8))) __bf16 bf16x8;
typedef __attribute__((ext_vector_type(4))) __bf16 bf16x4;
typedef __attribute__((ext_vector_type(4))) float f32x4;

static __device__ __forceinline__ float relu_f(float x){ return x > 0.f ? x : 0.f; }

// split fp32x4 -> bf16 hi/lo
static __device__ __forceinline__ void split4(const float* m, bf16x4& vh, bf16x4& vl){
    #pragma unroll
    for (int j = 0; j < 4; j++){
        float v = m[j];
        __bf16 h = (__bf16)v;
        vh[j] = h;
        vl[j] = (__bf16)(v - (float)h);
    }
}

// ---------------- CSR build ----------------
__global__ void k_count(const int* __restrict__ dst, int* __restrict__ cnt, int E){
    int i = blockIdx.x * blockDim.x + threadIdx.x;
    if (i < E) atomicAdd(&cnt[dst[i]], 1);
}

// single-block chunked Hillis-Steele exclusive scan; also emits dinv = 1/sqrt(deg+1)
__global__ void k_scan(const int* __restrict__ cnt, int* __restrict__ row_ptr,
                       float* __restrict__ dinv, int n){
    __shared__ int lds[1024];
    int t = threadIdx.x;
    int carry = 0;
    for (int base = 0; base < n; base += 1024){
        int idx = base + t;
        int v = (idx < n) ? cnt[idx] : 0;
        if (idx < n) dinv[idx] = 1.0f / sqrtf((float)(v + 1));
        __syncthreads();
        lds[t] = v;
        __syncthreads();
        for (int off = 1; off < 1024; off <<= 1){
            int add = (t >= off) ? lds[t - off] : 0;
            __syncthreads();
            lds[t] += add;
            __syncthreads();
        }
        int incl = lds[t];
        if (idx < n) row_ptr[idx] = carry + incl - v;   // exclusive
        carry += lds[1023];
    }
    if (t == 0) row_ptr[n] = carry;
}

__global__ void k_fill(const int* __restrict__ src, const int* __restrict__ dst,
                       const int* __restrict__ row_ptr, int* __restrict__ fill,
                       int* __restrict__ csr_src, int* __restrict__ csr_dst, int E){
    int i = blockIdx.x * blockDim.x + threadIdx.x;
    if (i < E){
        int d = dst[i];
        int pos = row_ptr[d] + atomicAdd(&fill[d], 1);
        csr_src[pos] = src[i];
        csr_dst[pos] = d;
    }
}

// ---------------- fused weight pack: fragment-ordered bf16 hi/lo, all weights in one launch ----
// Wp[((ks*256 + c)*4 + g)*8 + j] = W[ks*32 + g*8 + j][c]; optional src2 -> pack (src - src2).
struct PackDesc { const float* src; const float* src2; __bf16* ph; __bf16* pl; int K; int pad; };
struct PackArgs { PackDesc d[10]; };

__global__ void k_wpack_all(PackArgs a){
    PackDesc p = a.d[blockIdx.y];
    int total = (p.K >> 5) * 8192;
    int idx = blockIdx.x * 256 + threadIdx.x;
    if (idx >= total) return;
    int j = idx & 7, g = (idx >> 3) & 3, c = (idx >> 5) & 255, ks = idx >> 13;
    int k = ks * 32 + g * 8 + j;
    float v = p.src[(size_t)k * HD + c];
    if (p.src2) v -= p.src2[(size_t)k * HD + c];
    __bf16 h = (__bf16)v;
    p.ph[idx] = h;
    p.pl[idx] = (__bf16)(v - (float)h);
}

// ---------------- MFMA node GEMM: C[M,256] = A[M,K] @ W (+bias) ----------------
// 512 threads / 8 waves; wave w -> cols [32w, 32w+32); full row segment preloaded to regs.
template<int KS>
__global__ __launch_bounds__(512, 4) void k_gemm_mfma(
    const float* __restrict__ A,
    const __bf16* __restrict__ Wph, const __bf16* __restrict__ Wpl,
    const float* __restrict__ bias,
    float* __restrict__ C, int M, int K)
{
    __shared__ __bf16 mh[2][64][40];   // row stride 80B
    __shared__ __bf16 ml[2][64][40];
    int t = threadIdx.x;
    int m0 = blockIdx.x * 64;
    const int w = t >> 6, fr = t & 15, fg = (t & 63) >> 4;
    const int srow = t >> 3, skb = (t & 7) * 4;      // 8 threads cover 32 k per row
    int ar = m0 + srow; if (ar >= M) ar = M - 1;     // clamp loads; stores guarded
    const float* Arow = A + (size_t)ar * K + skb;
    const int c0 = w * 32 + fr;

    auto stage = [&](int buf, const float4& a){
        float m4[4] = {a.x, a.y, a.z, a.w};
        bf16x4 vh, vl;
        split4(m4, vh, vl);
        *(bf16x4*)&mh[buf][srow][skb] = vh;
        *(bf16x4*)&ml[buf][srow][skb] = vl;
    };

    f32x4 acc[4][2];
    #pragma unroll
    for (int i = 0; i < 4; i++)
        #pragma unroll
        for (int j = 0; j < 2; j++) acc[i][j] = (f32x4){0.f, 0.f, 0.f, 0.f};

    float4 rA[KS];
    #pragma unroll
    for (int c = 0; c < KS; c++) rA[c] = *(const float4*)(Arow + c * 32);

    stage(0, rA[0]);

    #pragma unroll
    for (int ks = 0; ks < KS; ++ks){
        bf16x8 bh[2], bl[2];
        #pragma unroll
        for (int nf = 0; nf < 2; nf++){
            size_t bi = ((size_t)(ks * 256 + c0 + nf * 16) * 4 + fg) * 8;
            bh[nf] = *(const bf16x8*)(Wph + bi);
            bl[nf] = *(const bf16x8*)(Wpl + bi);
        }
        __syncthreads();             // buf[ks&1] staged; prev readers of buf[(ks+1)&1] done
        const int cb = ks & 1;
        #pragma unroll
        for (int mf = 0; mf < 4; mf++){
            bf16x8 ah = *(const bf16x8*)&mh[cb][mf * 16 + fr][fg * 8];
            bf16x8 al = *(const bf16x8*)&ml[cb][mf * 16 + fr][fg * 8];
            #pragma unroll
            for (int nf = 0; nf < 2; nf++){
                acc[mf][nf] = __builtin_amdgcn_mfma_f32_16x16x32_bf16(ah, bh[nf], acc[mf][nf], 0, 0, 0);
                acc[mf][nf] = __builtin_amdgcn_mfma_f32_16x16x32_bf16(al, bh[nf], acc[mf][nf], 0, 0, 0);
                acc[mf][nf] = __builtin_amdgcn_mfma_f32_16x16x32_bf16(ah, bl[nf], acc[mf][nf], 0, 0, 0);
            }
        }
        if (ks + 1 < KS) stage(cb ^ 1, rA[ks + 1]);
    }

    float bj[2];
    #pragma unroll
    for (int nf = 0; nf < 2; nf++) bj[nf] = bias ? bias[c0 + nf * 16] : 0.f;
    #pragma unroll
    for (int mf = 0; mf < 4; mf++)
        #pragma unroll
        for (int reg = 0; reg < 4; reg++){
            int row = m0 + mf * 16 + fg * 4 + reg;   // C/D: col=lane&15, row=fg*4+reg (verified)
            if (row < M){
                #pragma unroll
                for (int nf = 0; nf < 2; nf++)
                    C[(size_t)row * HD + c0 + nf * 16] = acc[mf][nf][reg] + bj[nf];
            }
        }
}

// ---------------- dual-output MFMA node GEMM: stage A once, two weight sets ----------------
// waves 0-3 -> C1 cols [64w,64w+64) (bias1); waves 4-7 -> C2 (no bias).
// Per-column MFMA sequence identical to k_gemm_mfma -> bit-identical outputs.
template<int KS>
__global__ __launch_bounds__(512, 4) void k_gemm_mfma_dual(
    const float* __restrict__ A,
    const __bf16* __restrict__ Wph1, const __bf16* __restrict__ Wpl1,
    const float* __restrict__ bias1, float* __restrict__ C1,
    const __bf16* __restrict__ Wph2, const __bf16* __restrict__ Wpl2,
    float* __restrict__ C2, int M, int K)
{
    __shared__ __bf16 mh[2][64][40];
    __shared__ __bf16 ml[2][64][40];
    int t = threadIdx.x;
    int m0 = blockIdx.x * 64;
    const int w = t >> 6, grp = w >> 2, wl = w & 3;
    const int fr = t & 15, fg = (t & 63) >> 4;
    const int srow = t >> 3, skb = (t & 7) * 4;
    int ar = m0 + srow; if (ar >= M) ar = M - 1;
    const float* Arow = A + (size_t)ar * K + skb;
    const int c0 = wl * 64 + fr;
    const __bf16* Wph = grp ? Wph2 : Wph1;
    const __bf16* Wpl = grp ? Wpl2 : Wpl1;
    float* C = grp ? C2 : C1;

    auto stage = [&](int buf, const float4& a){
        float m4[4] = {a.x, a.y, a.z, a.w};
        bf16x4 vh, vl;
        split4(m4, vh, vl);
        *(bf16x4*)&mh[buf][srow][skb] = vh;
        *(bf16x4*)&ml[buf][srow][skb] = vl;
    };

    f32x4 acc[4][4];
    #pragma unroll
    for (int i = 0; i < 4; i++)
        #pragma unroll
        for (int j = 0; j < 4; j++) acc[i][j] = (f32x4){0.f, 0.f, 0.f, 0.f};

    float4 ra[2];
    ra[0] = *(const float4*)(Arow);
    stage(0, ra[0]);

    #pragma unroll
    for (int ks = 0; ks < KS; ++ks){
        if (ks + 1 < KS) ra[(ks + 1) & 1] = *(const float4*)(Arow + (ks + 1) * 32);
        bf16x8 bh[4], bl[4];
        #pragma unroll
        for (int nf = 0; nf < 4; nf++){
            size_t bi = ((size_t)(ks * 256 + c0 + nf * 16) * 4 + fg) * 8;
            bh[nf] = *(const bf16x8*)(Wph + bi);
            bl[nf] = *(const bf16x8*)(Wpl + bi);
        }
        __syncthreads();
        const int cb = ks & 1;
        #pragma unroll
        for (int mf = 0; mf < 4; mf++){
            bf16x8 ah = *(const bf16x8*)&mh[cb][mf * 16 + fr][fg * 8];
            bf16x8 al = *(const bf16x8*)&ml[cb][mf * 16 + fr][fg * 8];
            #pragma unroll
            for (int nf = 0; nf < 4; nf++){
                acc[mf][nf] = __builtin_amdgcn_mfma_f32_16x16x32_bf16(ah, bh[nf], acc[mf][nf], 0, 0, 0);
                acc[mf][nf] = __builtin_amdgcn_mfma_f32_16x16x32_bf16(al, bh[nf], acc[mf][nf], 0, 0, 0);
                acc[mf][nf] = __builtin_amdgcn_mfma_f32_16x16x32_bf16(ah, bl[nf], acc[mf][nf], 0, 0, 0);
            }
        }
        if (ks + 1 < KS) stage(cb ^ 1, ra[(ks + 1) & 1]);
    }

    float bj[4];
    #pragma unroll
    for (int nf = 0; nf < 4; nf++) bj[nf] = grp ? 0.f : bias1[c0 + nf * 16];
    #pragma unroll
    for (int mf = 0; mf < 4; mf++)
        #pragma unroll
        for (int reg = 0; reg < 4; reg++){
            int row = m0 + mf * 16 + fg * 4 + reg;
            if (row < M){
                #pragma unroll
                for (int nf = 0; nf < 4; nf++)
                    C[(size_t)row * HD + c0 + nf * 16] = acc[mf][nf][reg] + bj[nf];
            }
        }
}

// ---------------- GCN aggregate: 4 independent load/acc chains per wave ----------------
__global__ __launch_bounds__(256) void k_gcn_agg(const float* __restrict__ h,
                                                 const float* __restrict__ dinv,
                                                 const int* __restrict__ row_ptr,
                                                 const int* __restrict__ csr_src,
                                                 const float* __restrict__ bias,
                                                 float* __restrict__ out, int n){
    int wid = threadIdx.x >> 6, lane = threadIdx.x & 63;
    int i = blockIdx.x * 4 + wid;
    if (i >= n) return;
    float di = dinv[i];
    const float4* hp = (const float4*)h;
    float4 v = hp[(size_t)i * 64 + lane];
    float ax0 = v.x * di, ay0 = v.y * di, az0 = v.z * di, aw0 = v.w * di;  // self loop
    float ax1 = 0.f, ay1 = 0.f, az1 = 0.f, aw1 = 0.f;
    float ax2 = 0.f, ay2 = 0.f, az2 = 0.f, aw2 = 0.f;
    float ax3 = 0.f, ay3 = 0.f, az3 = 0.f, aw3 = 0.f;
    int e0 = row_ptr[i], e1 = row_ptr[i + 1];
    int e = e0;
    for (; e + 3 < e1; e += 4){
        int s0 = csr_src[e], s1 = csr_src[e + 1], s2 = csr_src[e + 2], s3 = csr_src[e + 3];
        float q0 = dinv[s0], q1 = dinv[s1], q2 = dinv[s2], q3 = dinv[s3];
        float4 u0 = hp[(size_t)s0 * 64 + lane];
        float4 u1 = hp[(size_t)s1 * 64 + lane];
        float4 u2 = hp[(size_t)s2 * 64 + lane];
        float4 u3 = hp[(size_t)s3 * 64 + lane];
        ax0 += u0.x * q0; ay0 += u0.y * q0; az0 += u0.z * q0; aw0 += u0.w * q0;
        ax1 += u1.x * q1; ay1 += u1.y * q1; az1 += u1.z * q1; aw1 += u1.w * q1;
        ax2 += u2.x * q2; ay2 += u2.y * q2; az2 += u2.z * q2; aw2 += u2.w * q2;
        ax3 += u3.x * q3; ay3 += u3.y * q3; az3 += u3.z * q3; aw3 += u3.w * q3;
    }
    for (; e < e1; e++){
        int s = csr_src[e];
        float q = dinv[s];
        float4 u = hp[(size_t)s * 64 + lane];
        ax0 += u.x * q; ay0 += u.y * q; az0 += u.z * q; aw0 += u.w * q;
    }
    float ax = (ax0 + ax1) + (ax2 + ax3);
    float ay = (ay0 + ay1) + (ay2 + ay3);
    float az = (az0 + az1) + (az2 + az3);
    float aw = (aw0 + aw1) + (aw2 + aw3);
    const float4 b = ((const float4*)bias)[lane];
    float4 o;
    o.x = relu_f(ax * di + b.x);
    o.y = relu_f(ay * di + b.y);
    o.z = relu_f(az * di + b.z);
    o.w = relu_f(aw * di + b.w);
    ((float4*)out)[(size_t)i * 64 + lane] = o;
}

// ---------------- fused EdgeConv: MFMA edge GEMM + max-aggregate (v3 structure, best measured) ---
// 512 threads / 8 waves / 32 cols per wave; XCD-bijective swizzle; 1-deep dbuf staging
// (R9's 4-deep ring regressed: VGPR 40->52 cut occupancy 62->43%; TLP already hid latency).
__global__ __launch_bounds__(512, 4) void k_edge_mfma(
    const float* __restrict__ A, const float* __restrict__ B,
    const __bf16* __restrict__ Wph, const __bf16* __restrict__ Wpl,
    const float* __restrict__ bias,
    const int* __restrict__ csr_src, const int* __restrict__ csr_dst,
    float* __restrict__ out, int E)
{
    __shared__ __bf16 mh[2][64][40];
    __shared__ __bf16 ml[2][64][40];
    __shared__ int sdst[64], ssrc[64];
    int t = threadIdx.x;
    // XCD-contiguous bijective swizzle (m204)
    int nwg = gridDim.x;
    int q = nwg >> 3, r = nwg & 7;
    int xc = blockIdx.x & 7;
    int bid = (xc < r ? xc * (q + 1) : r * (q + 1) + (xc - r) * q) + (blockIdx.x >> 3);
    int p0 = bid * 64;
    if (t < 64){
        int e = p0 + t; if (e >= E) e = E - 1;   // duplicate edge: idempotent under max
        sdst[t] = csr_dst[e];
        ssrc[t] = csr_src[e];
    }
    __syncthreads();

    const int w  = t >> 6;
    const int fr = t & 15;
    const int fg = (t & 63) >> 4;
    const int srow = t >> 3, skb = (t & 7) * 4;
    const float* Arow = A + (size_t)sdst[srow] * HD + skb;
    const float* Brow = B + (size_t)ssrc[srow] * HD + skb;
    const int c0 = w * 32 + fr;

    auto stage = [&](int buf, const float4& a, const float4& g){
        float m4[4] = {relu_f(a.x + g.x), relu_f(a.y + g.y), relu_f(a.z + g.z), relu_f(a.w + g.w)};
        bf16x4 vh, vl;
        split4(m4, vh, vl);
        *(bf16x4*)&mh[buf][srow][skb] = vh;
        *(bf16x4*)&ml[buf][srow][skb] = vl;
    };

    f32x4 acc[4][2];
    #pragma unroll
    for (int i = 0; i < 4; i++)
        #pragma unroll
        for (int j = 0; j < 2; j++) acc[i][j] = (f32x4){0.f, 0.f, 0.f, 0.f};

    {
        float4 a = *(const float4*)(Arow);
        float4 g = *(const float4*)(Brow);
        stage(0, a, g);
    }

    for (int ks = 0; ks < 8; ++ks){
        float4 a, g;
        if (ks < 7){                                  // issue next gather early
            a = *(const float4*)(Arow + (ks + 1) * 32);
            g = *(const float4*)(Brow + (ks + 1) * 32);
        }
        bf16x8 bh[2], bl[2];
        #pragma unroll
        for (int nf = 0; nf < 2; nf++){
            size_t bi = ((size_t)(ks * 256 + c0 + nf * 16) * 4 + fg) * 8;
            bh[nf] = *(const bf16x8*)(Wph + bi);
            bl[nf] = *(const bf16x8*)(Wpl + bi);
        }
        __syncthreads();             // buf[ks&1] staged; prev readers of buf[(ks+1)&1] done
        const int cb = ks & 1;
        #pragma unroll
        for (int mf = 0; mf < 4; mf++){
            bf16x8 ah = *(const bf16x8*)&mh[cb][mf * 16 + fr][fg * 8];
            bf16x8 al = *(const bf16x8*)&ml[cb][mf * 16 + fr][fg * 8];
            #pragma unroll
            for (int nf = 0; nf < 2; nf++){
                acc[mf][nf] = __builtin_amdgcn_mfma_f32_16x16x32_bf16(ah, bh[nf], acc[mf][nf], 0, 0, 0);
                acc[mf][nf] = __builtin_amdgcn_mfma_f32_16x16x32_bf16(al, bh[nf], acc[mf][nf], 0, 0, 0);
                acc[mf][nf] = __builtin_amdgcn_mfma_f32_16x16x32_bf16(ah, bl[nf], acc[mf][nf], 0, 0, 0);
            }
        }
        if (ks < 7) stage(cb ^ 1, a, g);
    }

    // epilogue: run-tracking scan over this thread's 16 rows (sdst non-decreasing in CSR order)
    float bj[2];
    #pragma unroll
    for (int nf = 0; nf < 2; nf++) bj[nf] = bias[c0 + nf * 16];
    int curd = sdst[fg * 4];
    float v[2];
    #pragma unroll
    for (int nf = 0; nf < 2; nf++) v[nf] = acc[0][nf][0] + bj[nf];
    #pragma unroll
    for (int mf = 0; mf < 4; mf++){
        #pragma unroll
        for (int reg = 0; reg < 4; reg++){
            if (mf == 0 && reg == 0) continue;
            int d = sdst[mf * 16 + fg * 4 + reg];
            if (d != curd){
                #pragma unroll
                for (int nf = 0; nf < 2; nf++)
                    if (v[nf] > 0.f)
                        atomicMax((int*)(out + (size_t)curd * HD + c0 + nf * 16), __float_as_int(v[nf]));
                curd = d;
                #pragma unroll
                for (int nf = 0; nf < 2; nf++) v[nf] = acc[mf][nf][reg] + bj[nf];
            } else {
                #pragma unroll
                for (int nf = 0; nf < 2; nf++) v[nf] = fmaxf(v[nf], acc[mf][nf][reg] + bj[nf]);
            }
        }
    }
    #pragma unroll
    for (int nf = 0; nf < 2; nf++)
        if (v[nf] > 0.f)
            atomicMax((int*)(out + (size_t)curd * HD + c0 + nf * 16), __float_as_int(v[nf]));
}

// ---------------- fused per-graph sum pool + head ----------------
__global__ __launch_bounds__(512) void k_pool_head(const float* __restrict__ xg,
                                                   const float* __restrict__ xe,
                                                   const int* __restrict__ batch,
                                                   const float* __restrict__ w1,
                                                   const float* __restrict__ b1,
                                                   const float* __restrict__ w2,
                                                   const float* __restrict__ b2,
                                                   float* __restrict__ out, int n){
    __shared__ float gp[512];
    __shared__ float red[256];
    int g = blockIdx.x, t = threadIdx.x;
    int lo, hi;
    { int l = 0, h = n; while (l < h){ int m = (l + h) >> 1; if (batch[m] < g) l = m + 1; else h = m; } lo = l; }
    { int l = lo, h = n; while (l < h){ int m = (l + h) >> 1; if (batch[m] < g + 1) l = m + 1; else h = m; } hi = l; }
    const float* sp = (t < 256) ? (xg + t) : (xe + (t - 256));
    float a0 = 0.f, a1 = 0.f;
    int i = lo;
    for (; i + 1 < hi; i += 2){
        a0 += sp[(size_t)i * HD];
        a1 += sp[(size_t)(i + 1) * HD];
    }
    if (i < hi) a0 += sp[(size_t)i * HD];
    gp[t] = a0 + a1;
    __syncthreads();
    if (t < 256){
        float acc = b1[t];
        #pragma unroll 4
        for (int k = 0; k < 512; k++) acc += gp[k] * w1[k * HD + t];
        red[t] = relu_f(acc) * w2[t];
    }
    __syncthreads();
    for (int s = 128; s > 0; s >>= 1){
        if (t < s) red[t] += red[t + s];
        __syncthreads();
    }
    if (t == 0) out[g] = red[0] + b2[0];
}

extern "C" void kernel_launch(void* const* d_in, const int* in_sizes, int n_in,
                              void* d_out, int out_size, void* d_ws, size_t ws_size,
                              hipStream_t stream){
    const float* x      = (const float*)d_in[0];
    const int*   ei     = (const int*)d_in[1];
    const int*   batch  = (const int*)d_in[2];
    const float* gcn_w[4] = {(const float*)d_in[3], (const float*)d_in[5], (const float*)d_in[7], (const float*)d_in[9]};
    const float* gcn_b[4] = {(const float*)d_in[4], (const float*)d_in[6], (const float*)d_in[8], (const float*)d_in[10]};
    const float* ec1_w1 = (const float*)d_in[11]; const float* ec1_b1 = (const float*)d_in[12];
    const float* ec1_w2 = (const float*)d_in[13]; const float* ec1_b2 = (const float*)d_in[14];
    const float* ec2_w1 = (const float*)d_in[15]; const float* ec2_b1 = (const float*)d_in[16];
    const float* ec2_w2 = (const float*)d_in[17]; const float* ec2_b2 = (const float*)d_in[18];
    const float* fc1_w  = (const float*)d_in[19]; const float* fc1_b  = (const float*)d_in[20];
    const float* out_w  = (const float*)d_in[21]; const float* out_b  = (const float*)d_in[22];

    const int N = in_sizes[2];
    const int E = in_sizes[1] / 2;
    const int F = in_sizes[0] / N;       // 128
    const int* src = ei;
    const int* dst = ei + E;
    const int GB64 = (N + 63) / 64;      // node-GEMM grid
    const int EB   = (E + 63) / 64;      // edge grid

    char* w = (char*)d_ws;
    auto alloc = [&](size_t bytes) -> char* {
        char* p = w;
        w += (bytes + 255) & ~(size_t)255;
        return p;
    };
    int*   cnt     = (int*)alloc((size_t)N * 4);
    int*   fillc   = (int*)alloc((size_t)N * 4);
    int*   row_ptr = (int*)alloc((size_t)(N + 1) * 4);
    int*   csr_src = (int*)alloc((size_t)E * 4);
    int*   csr_dst = (int*)alloc((size_t)E * 4);
    float* dinv    = (float*)alloc((size_t)N * 4);
    float* act     = (float*)alloc((size_t)N * HD * 4);
    float* hbuf    = (float*)alloc((size_t)N * HD * 4);
    float* Bbuf    = (float*)alloc((size_t)N * HD * 4);
    float* xebuf   = (float*)alloc((size_t)N * HD * 4);
    // weight packs (bf16 hi/lo, fragment-ordered)
    auto packa = [&](int K) -> __bf16* { return (__bf16*)alloc((size_t)K * 256 * 2); };
    __bf16* pg1h = packa(128); __bf16* pg1l = packa(128);
    __bf16* pg2h = packa(256); __bf16* pg2l = packa(256);
    __bf16* pg3h = packa(256); __bf16* pg3l = packa(256);
    __bf16* pg4h = packa(256); __bf16* pg4l = packa(256);
    __bf16* pe1ah = packa(128); __bf16* pe1al = packa(128);
    __bf16* pe1bh = packa(128); __bf16* pe1bl = packa(128);
    __bf16* pe2ah = packa(256); __bf16* pe2al = packa(256);
    __bf16* pe2bh = packa(256); __bf16* pe2bl = packa(256);
    __bf16* w2h1 = packa(256); __bf16* w2l1 = packa(256);
    __bf16* w2h2 = packa(256); __bf16* w2l2 = packa(256);

    // ---- CSR + deg norm ----
    hipMemsetAsync(cnt, 0, (size_t)N * 4, stream);
    hipMemsetAsync(fillc, 0, (size_t)N * 4, stream);
    k_count<<<(E + 255) / 256, 256, 0, stream>>>(dst, cnt, E);
    k_scan<<<1, 1024, 0, stream>>>(cnt, row_ptr, dinv, N);
    k_fill<<<(E + 255) / 256, 256, 0, stream>>>(src, dst, row_ptr, fillc, csr_src, csr_dst, E);

    // ---- all weight packs in ONE launch (wdiff folded in via src2) ----
    PackArgs pa;
    pa.d[0] = {gcn_w[0],                  nullptr,                    pg1h,  pg1l,  F,  0};
    pa.d[1] = {gcn_w[1],                  nullptr,                    pg2h,  pg2l,  HD, 0};
    pa.d[2] = {gcn_w[2],                  nullptr,                    pg3h,  pg3l,  HD, 0};
    pa.d[3] = {gcn_w[3],                  nullptr,                    pg4h,  pg4l,  HD, 0};
    pa.d[4] = {ec1_w1,                    ec1_w1 + (size_t)F * HD,    pe1ah, pe1al, F,  0};
    pa.d[5] = {ec1_w1 + (size_t)F * HD,   nullptr,                    pe1bh, pe1bl, F,  0};
    pa.d[6] = {ec2_w1,                    ec2_w1 + (size_t)HD * HD,   pe2ah, pe2al, HD, 0};
    pa.d[7] = {ec2_w1 + (size_t)HD * HD,  nullptr,                    pe2bh, pe2bl, HD, 0};
    pa.d[8] = {ec1_w2,                    nullptr,                    w2h1,  w2l1,  HD, 0};
    pa.d[9] = {ec2_w2,                    nullptr,                    w2h2,  w2l2,  HD, 0};
    k_wpack_all<<<dim3(256, 10), 256, 0, stream>>>(pa);

    // ---- GCN branch ----
    k_gemm_mfma<4><<<GB64, 512, 0, stream>>>(x, pg1h, pg1l, nullptr, hbuf, N, F);
    k_gcn_agg<<<(N + 3) / 4, 256, 0, stream>>>(hbuf, dinv, row_ptr, csr_src, gcn_b[0], act, N);
    const __bf16* pgh[3] = {pg2h, pg3h, pg4h};
    const __bf16* pgl[3] = {pg2l, pg3l, pg4l};
    for (int l = 0; l < 3; l++){
        k_gemm_mfma<8><<<GB64, 512, 0, stream>>>(act, pgh[l], pgl[l], nullptr, hbuf, N, HD);
        k_gcn_agg<<<(N + 3) / 4, 256, 0, stream>>>(hbuf, dinv, row_ptr, csr_src, gcn_b[l + 1], act, N);
    }

    // ---- EdgeConv 1 (input x, K=F): both node GEMMs in one pass ----
    k_gemm_mfma_dual<4><<<GB64, 512, 0, stream>>>(x, pe1ah, pe1al, ec1_b1, hbuf,
                                                  pe1bh, pe1bl, Bbuf, N, F);
    hipMemsetAsync(xebuf, 0, (size_t)N * HD * 4, stream);
    k_edge_mfma<<<EB, 512, 0, stream>>>(hbuf, Bbuf, w2h1, w2l1, ec1_b2, csr_src, csr_dst, xebuf, E);

    // ---- EdgeConv 2 (input xe, K=HD): both node GEMMs in one pass ----
    k_gemm_mfma_dual<8><<<GB64, 512, 0, stream>>>(xebuf, pe2ah, pe2al, ec2_b1, hbuf,
                                                  pe2bh, pe2bl, Bbuf, N, HD);
    hipMemsetAsync(xebuf, 0, (size_t)N * HD * 4, stream);
    k_edge_mfma<<<EB, 512, 0, stream>>>(hbuf, Bbuf, w2h2, w2l2, ec2_b2, csr_src, csr_dst, xebuf, E);

    // ---- fused pool + head ----
    k_pool_head<<<64, 512, 0, stream>>>(act, xebuf, batch, fc1_w, fc1_b, out_w, out_b, (float*)d_out, N);
}